// Round 1
// baseline (251.727 us; speedup 1.0000x reference)
//
#include <hip/hip_runtime.h>

// ---------------------------------------------------------------------------
// GIN: 3 x (bucket gather-sum + (x+agg)@W + b, relu) + MLP head, bf16 MFMA.
// r7: 32-node buckets (was 64) -> grid 1563 (was 782).
//     Theory: all counters low (Mfma 2.9 / VALU 16 / HBM 12 / Occ 15.5) =>
//     latency/occupancy-bound. 782 blocks were all co-resident with no
//     refill (tail decay + 4-vs-3 block/CU imbalance). 1563 blocks exceed
//     the 4-block/CU residency cap (VGPR 88 -> 4 waves/SIMD quantum), so
//     CUs refill dynamically and occupancy holds at the cap.
//     6 dispatches: prep_all, bin_edges, sort_buckets, 2x fused_layer,
//     fused_l3_head.
// ---------------------------------------------------------------------------

typedef short short8 __attribute__((ext_vector_type(8)));
typedef float v4f __attribute__((ext_vector_type(4)));

#define NPB 32      // nodes per bucket
#define BCAP 512    // bucket capacity: mean 384, expected max ~459 (+6.5 sigma)
#define MAXB 2048   // >= nbuckets (1563)

__device__ inline unsigned short f2bf(float f) {
  union { float f; unsigned int u; } c; c.f = f;
  unsigned int u = c.u;
  return (unsigned short)((u + 0x7fffu + ((u >> 16) & 1u)) >> 16);  // RNE
}
__device__ inline float bfbits2f(unsigned int hi) {
  union { unsigned int u; float f; } c; c.u = hi; return c.f;
}
__device__ inline unsigned int pack2(float a, float b) {
  return (unsigned int)f2bf(a) | ((unsigned int)f2bf(b) << 16);
}
__device__ inline void add8(float* s, uint4 v) {
  s[0] += bfbits2f(v.x << 16); s[1] += bfbits2f(v.x & 0xffff0000u);
  s[2] += bfbits2f(v.y << 16); s[3] += bfbits2f(v.y & 0xffff0000u);
  s[4] += bfbits2f(v.z << 16); s[5] += bfbits2f(v.z & 0xffff0000u);
  s[6] += bfbits2f(v.w << 16); s[7] += bfbits2f(v.w & 0xffff0000u);
}
__device__ inline int wave_incl_scan_int(int v, int lane) {
#pragma unroll
  for (int off = 1; off < 64; off <<= 1) {
    int t = __shfl_up(v, off, 64);
    if (lane >= off) v += t;
  }
  return v;
}

// ------------------------- prep: weights + x->bf16 + zero bcnt --------------
__global__ __launch_bounds__(256) void prep_all(
    const float* __restrict__ W0, const float* __restrict__ W1, const float* __restrict__ W2,
    const float* __restrict__ Wm1, const float* __restrict__ Wm2,
    unsigned short* __restrict__ W0T, unsigned short* __restrict__ W1T,
    unsigned short* __restrict__ W2T, unsigned short* __restrict__ Wm1T,
    unsigned short* __restrict__ Wm2T,
    const float* __restrict__ x, unsigned short* __restrict__ xb, int n8,
    int* __restrict__ bcnt) {
  int i = blockIdx.x * 256 + threadIdx.x;
  if (i < MAXB) bcnt[i] = 0;
  if (i < n8) {
    const float4* p = (const float4*)x;
    float4 a = p[2 * (size_t)i], b = p[2 * (size_t)i + 1];
    uint4 o;
    o.x = pack2(a.x, a.y); o.y = pack2(a.z, a.w);
    o.z = pack2(b.x, b.y); o.w = pack2(b.z, b.w);
    ((uint4*)xb)[i] = o;
  }
  if (i < 49152) {                       // 3 x [128,128] -> [128n][128k]
    int w = i / 16384, r = i % 16384;
    int nn = r >> 7, k = r & 127;
    const float* W = (w == 0) ? W0 : (w == 1) ? W1 : W2;
    unsigned short* O = (w == 0) ? W0T : (w == 1) ? W1T : W2T;
    O[r] = f2bf(W[k * 128 + nn]);
  } else if (i < 49152 + 32768) {        // Wm1 [128,256] -> [256n][128k]
    int r = i - 49152;
    int nn = r >> 7, k = r & 127;
    Wm1T[r] = f2bf(Wm1[k * 256 + nn]);
  } else if (i < 49152 + 32768 + 4096) { // Wm2 [256,10] -> [16n][256k], pad 0
    int r = i - 49152 - 32768;
    int nn = r >> 8, k = r & 255;
    Wm2T[r] = (nn < 10) ? f2bf(Wm2[k * 10 + nn]) : (unsigned short)0;
  }
}

// ------------------------- bin edges into 32-node buckets -------------------
// entry = (src << 5) | (dst & 31); bucket = dst >> 5.
__global__ __launch_bounds__(256) void bin_edges(
    const int* __restrict__ src, const int* __restrict__ dst, int E, int per,
    int* __restrict__ bcnt, int* __restrict__ bucketA, int nbuckets) {
  __shared__ int hist[MAXB];
  __shared__ int base[MAXB];
  const int tid = threadIdx.x;
  const int e0 = blockIdx.x * per;
  const int e1 = (e0 + per < E) ? e0 + per : E;
  for (int j = tid; j < nbuckets; j += 256) hist[j] = 0;
  __syncthreads();
  for (int i = e0 + tid; i < e1; i += 256) atomicAdd(&hist[dst[i] >> 5], 1);
  __syncthreads();
  for (int j = tid; j < nbuckets; j += 256) {
    int h = hist[j];
    base[j] = h ? atomicAdd(&bcnt[j], h) : 0;
  }
  __syncthreads();
  for (int i = e0 + tid; i < e1; i += 256) {
    int d = dst[i], s = src[i];
    int b = d >> 5;
    int r = atomicAdd(&base[b], 1);
    bucketA[(size_t)b * BCAP + r] = (s << 5) | (d & 31);
  }
}

// ------------------------- per-bucket counting sort (once) ------------------
// Produces srcsS[b*BCAP + p] sorted by local node, boffs[b*33 + 0..32].
__global__ __launch_bounds__(256) void sort_buckets(
    const int* __restrict__ bcnt, const int* __restrict__ bucketA,
    int* __restrict__ srcsS, int* __restrict__ boffs) {
  __shared__ int rawE[BCAP];
  __shared__ int hist[NPB], cur[NPB], offs[NPB + 1];
  const int tid = threadIdx.x;
  const int b = blockIdx.x;
  const int cnt = bcnt[b];
  for (int i = tid; i < cnt; i += 256) rawE[i] = bucketA[(size_t)b * BCAP + i];
  if (tid < NPB) hist[tid] = 0;
  __syncthreads();
  for (int i = tid; i < cnt; i += 256) atomicAdd(&hist[rawE[i] & 31], 1);
  __syncthreads();
  if (tid < NPB) {
    int v = hist[tid];
    int incl = wave_incl_scan_int(v, tid);
    offs[tid] = incl - v;
    cur[tid] = incl - v;
    if (tid == NPB - 1) offs[NPB] = incl;
  }
  __syncthreads();
  for (int i = tid; i < cnt; i += 256) {
    int e = rawE[i];
    int p = atomicAdd(&cur[e & 31], 1);
    srcsS[(size_t)b * BCAP + p] = e >> 5;
  }
  if (tid < NPB + 1) boffs[b * (NPB + 1) + tid] = offs[tid];
}

// ------------------------- fused layer (layers 1,2) -------------------------
// Block = bucket = 32 nodes. Stream sorted srcs -> LDS; barrier-free gather
// with deep load pipelining; MFMA 32x128 (2x2 waves, wave 16m x 64n, K=128).
__global__ __launch_bounds__(256) void fused_layer(
    const unsigned short* __restrict__ X, const int* __restrict__ bcnt,
    const int* __restrict__ srcsS, const int* __restrict__ boffs,
    const unsigned short* __restrict__ BT, const float* __restrict__ bias,
    unsigned short* __restrict__ C, int M) {
  __shared__ __align__(16) unsigned short As[NPB * 136];
  __shared__ int srcS[BCAP];
  __shared__ int offs[NPB + 1];
  const int tid = threadIdx.x;
  const int lane = tid & 63;
  const int b = blockIdx.x;
  const int blk = b * NPB;
  const int cnt = bcnt[b];

  if (tid < NPB + 1) offs[tid] = boffs[b * (NPB + 1) + tid];
  for (int i = tid; i < cnt; i += 256) srcS[i] = srcsS[(size_t)b * BCAP + i];
  __syncthreads();

  // ---- gather: 2 sweeps x 16 nodes; 16 lanes x 16B per row; NO barriers
  const int l = tid & 15, g = tid >> 4;
  const uint4* base = (const uint4*)X;
#pragma unroll
  for (int s2 = 0; s2 < 2; ++s2) {
    int nl = s2 * 16 + g;
    int node = blk + nl;
    float s[8] = {0, 0, 0, 0, 0, 0, 0, 0};
    if (node < M) {
      add8(s, base[(size_t)node * 16 + l]);
      int beg = offs[nl], c = offs[nl + 1] - beg;
      int j = 0;
      for (; j + 8 <= c; j += 8) {
        int i0 = srcS[beg + j + 0], i1 = srcS[beg + j + 1];
        int i2 = srcS[beg + j + 2], i3 = srcS[beg + j + 3];
        int i4 = srcS[beg + j + 4], i5 = srcS[beg + j + 5];
        int i6 = srcS[beg + j + 6], i7 = srcS[beg + j + 7];
        uint4 v0 = base[(size_t)i0 * 16 + l];
        uint4 v1 = base[(size_t)i1 * 16 + l];
        uint4 v2 = base[(size_t)i2 * 16 + l];
        uint4 v3 = base[(size_t)i3 * 16 + l];
        uint4 v4 = base[(size_t)i4 * 16 + l];
        uint4 v5 = base[(size_t)i5 * 16 + l];
        uint4 v6 = base[(size_t)i6 * 16 + l];
        uint4 v7 = base[(size_t)i7 * 16 + l];
        add8(s, v0); add8(s, v1); add8(s, v2); add8(s, v3);
        add8(s, v4); add8(s, v5); add8(s, v6); add8(s, v7);
      }
      if (j + 4 <= c) {
        int i0 = srcS[beg + j + 0], i1 = srcS[beg + j + 1];
        int i2 = srcS[beg + j + 2], i3 = srcS[beg + j + 3];
        uint4 v0 = base[(size_t)i0 * 16 + l];
        uint4 v1 = base[(size_t)i1 * 16 + l];
        uint4 v2 = base[(size_t)i2 * 16 + l];
        uint4 v3 = base[(size_t)i3 * 16 + l];
        add8(s, v0); add8(s, v1); add8(s, v2); add8(s, v3);
        j += 4;
      }
      if (j + 2 <= c) {
        int i0 = srcS[beg + j + 0], i1 = srcS[beg + j + 1];
        uint4 v0 = base[(size_t)i0 * 16 + l];
        uint4 v1 = base[(size_t)i1 * 16 + l];
        add8(s, v0); add8(s, v1);
        j += 2;
      }
      if (j < c) add8(s, base[(size_t)srcS[beg + j] * 16 + l]);
    }
    uint4 o;
    o.x = pack2(s[0], s[1]); o.y = pack2(s[2], s[3]);
    o.z = pack2(s[4], s[5]); o.w = pack2(s[6], s[7]);
    *(uint4*)&As[nl * 136 + l * 8] = o;
  }
  __syncthreads();

  // ---- MFMA: 4 waves 2x2; wave tile 16m x 64n; K=128
  const int w = tid >> 6;
  const int wm = w & 1, wn = w >> 1;
  const int l15 = lane & 15, quad = lane >> 4;
  const int mb = wm * 16, nb2 = wn * 64;

  const unsigned short* bp[4];
#pragma unroll
  for (int nf = 0; nf < 4; ++nf)
    bp[nf] = BT + (size_t)(nb2 + nf * 16 + l15) * 128 + quad * 8;

  v4f acc[4];
#pragma unroll
  for (int nf = 0; nf < 4; ++nf) acc[nf] = (v4f)0.f;

#pragma unroll
  for (int k0 = 0; k0 < 128; k0 += 32) {
    short8 a = *(const short8*)&As[(mb + l15) * 136 + k0 + quad * 8];
    short8 bv[4];
#pragma unroll
    for (int nf = 0; nf < 4; ++nf) bv[nf] = *(const short8*)(bp[nf] + k0);
#pragma unroll
    for (int nf = 0; nf < 4; ++nf)
      acc[nf] = __builtin_amdgcn_mfma_f32_16x16x32_bf16(a, bv[nf], acc[nf], 0, 0, 0);
  }

#pragma unroll
  for (int r = 0; r < 4; ++r) {
    int grow = blk + mb + quad * 4 + r;
    if (grow >= M) continue;
#pragma unroll
    for (int nf = 0; nf < 4; ++nf) {
      int gcol = nb2 + nf * 16 + l15;
      float v = acc[nf][r] + bias[gcol];
      C[(size_t)grow * 128 + gcol] = f2bf(fmaxf(v, 0.f));
    }
  }
}

// ------------------------- fused layer 3 + MLP head -------------------------
// Same gather+MFMA as fused_layer, then head entirely in LDS:
//   t  = relu((x+agg)@W2 + b2)      -> back into As
//   Hs = relu(t @ Wm1 + bm1)        -> Hs (aliases As+srcS)
//   out= Hs @ Wm2 + bm2             (Wm2T zero-padded to 16 cols)
__global__ __launch_bounds__(256) void fused_l3_head(
    const unsigned short* __restrict__ X, const int* __restrict__ bcnt,
    const int* __restrict__ srcsS, const int* __restrict__ boffs,
    const unsigned short* __restrict__ W2T, const float* __restrict__ b2,
    const unsigned short* __restrict__ Wm1T, const float* __restrict__ bm1,
    const unsigned short* __restrict__ Wm2T, const float* __restrict__ bm2,
    float* __restrict__ out, int M, int NOUT) {
  __shared__ __align__(16) unsigned char lds[NPB * 264 * 2];  // Hs 16.9KB
  unsigned short* As = (unsigned short*)lds;                  // 8.7KB
  int* srcS = (int*)(lds + NPB * 136 * 2);                    // 2KB after As
  unsigned short* Hs = (unsigned short*)lds;                  // aliases both
  __shared__ int offs[NPB + 1];
  const int tid = threadIdx.x;
  const int lane = tid & 63;
  const int b = blockIdx.x;
  const int blk = b * NPB;
  const int cnt = bcnt[b];

  if (tid < NPB + 1) offs[tid] = boffs[b * (NPB + 1) + tid];
  for (int i = tid; i < cnt; i += 256) srcS[i] = srcsS[(size_t)b * BCAP + i];
  __syncthreads();

  // ---- gather (same as fused_layer)
  const int l = tid & 15, g = tid >> 4;
  const uint4* base = (const uint4*)X;
#pragma unroll
  for (int s2 = 0; s2 < 2; ++s2) {
    int nl = s2 * 16 + g;
    int node = blk + nl;
    float s[8] = {0, 0, 0, 0, 0, 0, 0, 0};
    if (node < M) {
      add8(s, base[(size_t)node * 16 + l]);
      int beg = offs[nl], c = offs[nl + 1] - beg;
      int j = 0;
      for (; j + 8 <= c; j += 8) {
        int i0 = srcS[beg + j + 0], i1 = srcS[beg + j + 1];
        int i2 = srcS[beg + j + 2], i3 = srcS[beg + j + 3];
        int i4 = srcS[beg + j + 4], i5 = srcS[beg + j + 5];
        int i6 = srcS[beg + j + 6], i7 = srcS[beg + j + 7];
        uint4 v0 = base[(size_t)i0 * 16 + l];
        uint4 v1 = base[(size_t)i1 * 16 + l];
        uint4 v2 = base[(size_t)i2 * 16 + l];
        uint4 v3 = base[(size_t)i3 * 16 + l];
        uint4 v4 = base[(size_t)i4 * 16 + l];
        uint4 v5 = base[(size_t)i5 * 16 + l];
        uint4 v6 = base[(size_t)i6 * 16 + l];
        uint4 v7 = base[(size_t)i7 * 16 + l];
        add8(s, v0); add8(s, v1); add8(s, v2); add8(s, v3);
        add8(s, v4); add8(s, v5); add8(s, v6); add8(s, v7);
      }
      if (j + 4 <= c) {
        int i0 = srcS[beg + j + 0], i1 = srcS[beg + j + 1];
        int i2 = srcS[beg + j + 2], i3 = srcS[beg + j + 3];
        uint4 v0 = base[(size_t)i0 * 16 + l];
        uint4 v1 = base[(size_t)i1 * 16 + l];
        uint4 v2 = base[(size_t)i2 * 16 + l];
        uint4 v3 = base[(size_t)i3 * 16 + l];
        add8(s, v0); add8(s, v1); add8(s, v2); add8(s, v3);
        j += 4;
      }
      if (j + 2 <= c) {
        int i0 = srcS[beg + j + 0], i1 = srcS[beg + j + 1];
        uint4 v0 = base[(size_t)i0 * 16 + l];
        uint4 v1 = base[(size_t)i1 * 16 + l];
        add8(s, v0); add8(s, v1);
        j += 2;
      }
      if (j < c) add8(s, base[(size_t)srcS[beg + j] * 16 + l]);
    }
    uint4 o;
    o.x = pack2(s[0], s[1]); o.y = pack2(s[2], s[3]);
    o.z = pack2(s[4], s[5]); o.w = pack2(s[6], s[7]);
    *(uint4*)&As[nl * 136 + l * 8] = o;
  }
  __syncthreads();

  // ---- layer-3 MFMA: 32x128, K=128
  const int w = tid >> 6;
  const int wm = w & 1, wn = w >> 1;
  const int l15 = lane & 15, quad = lane >> 4;
  const int mb = wm * 16, nb2 = wn * 64;

  v4f acc[4];
#pragma unroll
  for (int nf = 0; nf < 4; ++nf) acc[nf] = (v4f)0.f;

#pragma unroll
  for (int k0 = 0; k0 < 128; k0 += 32) {
    short8 a = *(const short8*)&As[(mb + l15) * 136 + k0 + quad * 8];
    short8 bv[4];
#pragma unroll
    for (int nf = 0; nf < 4; ++nf)
      bv[nf] = *(const short8*)(W2T + (size_t)(nb2 + nf * 16 + l15) * 128 + quad * 8 + k0);
#pragma unroll
    for (int nf = 0; nf < 4; ++nf)
      acc[nf] = __builtin_amdgcn_mfma_f32_16x16x32_bf16(a, bv[nf], acc[nf], 0, 0, 0);
  }
  __syncthreads();  // all As reads done before rewrite

  // t = relu(acc + b2) -> back into As (local rows 0..31, cols 0..127)
#pragma unroll
  for (int r = 0; r < 4; ++r) {
    int row = mb + quad * 4 + r;
#pragma unroll
    for (int nf = 0; nf < 4; ++nf) {
      int col = nb2 + nf * 16 + l15;
      As[row * 136 + col] = f2bf(fmaxf(acc[nf][r] + b2[col], 0.f));
    }
  }
  __syncthreads();

  // ---- head phase A: Hm = relu(t @ Wm1 + bm1), 32x256, K=128
  const int nbH = wn * 128;
  v4f acc2[8];
#pragma unroll
  for (int nf = 0; nf < 8; ++nf) acc2[nf] = (v4f)0.f;

#pragma unroll
  for (int k0 = 0; k0 < 128; k0 += 32) {
    short8 a = *(const short8*)&As[(mb + l15) * 136 + k0 + quad * 8];
#pragma unroll
    for (int nf = 0; nf < 8; ++nf) {
      short8 bb = *(const short8*)(Wm1T + (size_t)(nbH + nf * 16 + l15) * 128 + quad * 8 + k0);
      acc2[nf] = __builtin_amdgcn_mfma_f32_16x16x32_bf16(a, bb, acc2[nf], 0, 0, 0);
    }
  }
  __syncthreads();  // As reads done; Hs may overwrite

#pragma unroll
  for (int r = 0; r < 4; ++r) {
    int row = mb + quad * 4 + r;
#pragma unroll
    for (int nf = 0; nf < 8; ++nf) {
      int col = nbH + nf * 16 + l15;
      Hs[row * 264 + col] = f2bf(fmaxf(acc2[nf][r] + bm1[col], 0.f));
    }
  }
  __syncthreads();

  // ---- head phase B: out = Hs @ Wm2 + bm2; 32x16, K=256; waves 0,1 only
  if (w < 2) {
    const int rowl = w * 16 + l15;
    const unsigned short* bp2 = Wm2T + (size_t)l15 * 256 + quad * 8;
    v4f acc3 = (v4f)0.f;
#pragma unroll
    for (int k0 = 0; k0 < 256; k0 += 32)
      acc3 = __builtin_amdgcn_mfma_f32_16x16x32_bf16(
          *(const short8*)&Hs[rowl * 264 + k0 + quad * 8],
          *(const short8*)(bp2 + k0), acc3, 0, 0, 0);
    float bb = (l15 < NOUT) ? bm2[l15] : 0.f;
#pragma unroll
    for (int r = 0; r < 4; ++r) {
      int grow = blk + w * 16 + quad * 4 + r;
      if (grow < M && l15 < NOUT) out[(size_t)grow * NOUT + l15] = acc3[r] + bb;
    }
  }
}

// ---------------------------------------------------------------------------

extern "C" void kernel_launch(void* const* d_in, const int* in_sizes, int n_in,
                              void* d_out, int out_size, void* d_ws, size_t ws_size,
                              hipStream_t stream) {
  const float* x   = (const float*)d_in[0];
  const int*   ei  = (const int*)d_in[1];
  const float* W0  = (const float*)d_in[2];
  const float* b0  = (const float*)d_in[3];
  const float* W1  = (const float*)d_in[4];
  const float* b1  = (const float*)d_in[5];
  const float* W2  = (const float*)d_in[6];
  const float* b2  = (const float*)d_in[7];
  const float* Wm1 = (const float*)d_in[8];
  const float* bm1 = (const float*)d_in[9];
  const float* Wm2 = (const float*)d_in[10];
  const float* bm2 = (const float*)d_in[11];
  float* out = (float*)d_out;

  const int D = 128;
  const int N = in_sizes[0] / D;   // 50000
  const int E = in_sizes[1] / 2;   // 600000
  const int L = in_sizes[11];      // 10
  const int nb = (N + NPB - 1) / NPB;  // 1563 buckets == layer tiles

  const int* srcv = ei;
  const int* dstv = ei + E;

  char* ws = (char*)d_ws;
  size_t off = 0;
  auto alloc = [&](size_t bytes) -> void* {
    void* p = ws + off;
    off = (off + bytes + 255) & ~(size_t)255;
    return p;
  };
  int* bcnt    = (int*)alloc((size_t)MAXB * 4);
  int* bucketA = (int*)alloc((size_t)nb * BCAP * 4);
  int* srcsS   = (int*)alloc((size_t)nb * BCAP * 4);
  int* boffs   = (int*)alloc((size_t)nb * (NPB + 1) * 4);
  unsigned short* xb   = (unsigned short*)alloc((size_t)N * 128 * 2);
  unsigned short* h1   = (unsigned short*)alloc((size_t)N * 128 * 2);
  unsigned short* h2   = (unsigned short*)alloc((size_t)N * 128 * 2);
  unsigned short* W0T  = (unsigned short*)alloc(128 * 128 * 2);
  unsigned short* W1T  = (unsigned short*)alloc(128 * 128 * 2);
  unsigned short* W2T  = (unsigned short*)alloc(128 * 128 * 2);
  unsigned short* Wm1T = (unsigned short*)alloc(256 * 128 * 2);
  unsigned short* Wm2T = (unsigned short*)alloc(16 * 256 * 2);
  (void)ws_size; (void)n_in; (void)out_size;

  const int tpb = 256;
  int n8 = N * 16;
  prep_all<<<dim3((n8 + tpb - 1) / tpb), dim3(tpb), 0, stream>>>(
      W0, W1, W2, Wm1, Wm2, W0T, W1T, W2T, Wm1T, Wm2T, x, xb, n8, bcnt);

  const int nbin = 256;
  int per = (E + nbin - 1) / nbin;
  bin_edges<<<dim3(nbin), dim3(tpb), 0, stream>>>(srcv, dstv, E, per, bcnt, bucketA, nb);
  sort_buckets<<<dim3(nb), dim3(tpb), 0, stream>>>(bcnt, bucketA, srcsS, boffs);

  dim3 lgrid(nb);
  fused_layer<<<lgrid, dim3(tpb), 0, stream>>>(xb, bcnt, srcsS, boffs, W0T, b0, h1, N);
  fused_layer<<<lgrid, dim3(tpb), 0, stream>>>(h1, bcnt, srcsS, boffs, W1T, b1, h2, N);
  fused_l3_head<<<lgrid, dim3(tpb), 0, stream>>>(h2, bcnt, srcsS, boffs, W2T, b2,
                                                 Wm1T, bm1, Wm2T, bm2, out, N, L);
}

// Round 2
// 232.012 us; speedup vs baseline: 1.0850x; 1.0850x over previous
//
#include <hip/hip_runtime.h>

// ---------------------------------------------------------------------------
// GIN: 3 x (bucket gather-sum + (x+agg)@W + b, relu) + MLP head, bf16 MFMA.
// r8: fp8(e4m3) neighbor gather. Evidence: r6->r7 doubled occupancy with
//     IDENTICAL 65us layer time and FETCH pinned at 60.8MB @ ~1TB/s =>
//     random L2-miss service rate is the wall, not parallelism. Fix: halve
//     miss volume. Gathered rows stored as 128B fp8 (was 256B bf16); self
//     term stays bf16 (streaming); accum stays f32. Buckets back to 64
//     nodes (r6) - fewer blocks => less weight re-read traffic.
//     6 dispatches: prep_all, bin_edges, sort_buckets, 2x fused_layer,
//     fused_l3_head.
// ---------------------------------------------------------------------------

typedef short short8 __attribute__((ext_vector_type(8)));
typedef float v4f __attribute__((ext_vector_type(4)));
typedef float v2f __attribute__((ext_vector_type(2)));

#define BCAP 1024   // bucket capacity: avg 768 edges, +9 sigma head-room
#define MAXB 1024   // >= nbuckets (782)

__device__ inline unsigned short f2bf(float f) {
  union { float f; unsigned int u; } c; c.f = f;
  unsigned int u = c.u;
  return (unsigned short)((u + 0x7fffu + ((u >> 16) & 1u)) >> 16);  // RNE
}
__device__ inline float bfbits2f(unsigned int hi) {
  union { unsigned int u; float f; } c; c.u = hi; return c.f;
}
__device__ inline unsigned int pack2(float a, float b) {
  return (unsigned int)f2bf(a) | ((unsigned int)f2bf(b) << 16);
}
__device__ inline void add8(float* s, uint4 v) {
  s[0] += bfbits2f(v.x << 16); s[1] += bfbits2f(v.x & 0xffff0000u);
  s[2] += bfbits2f(v.y << 16); s[3] += bfbits2f(v.y & 0xffff0000u);
  s[4] += bfbits2f(v.z << 16); s[5] += bfbits2f(v.z & 0xffff0000u);
  s[6] += bfbits2f(v.w << 16); s[7] += bfbits2f(v.w & 0xffff0000u);
}
// decode 8 fp8 (e4m3, HW format) and accumulate
__device__ inline void addf8(float* s, uint2 v) {
  v2f p;
  p = __builtin_amdgcn_cvt_pk_f32_fp8(v.x, false); s[0] += p.x; s[1] += p.y;
  p = __builtin_amdgcn_cvt_pk_f32_fp8(v.x, true);  s[2] += p.x; s[3] += p.y;
  p = __builtin_amdgcn_cvt_pk_f32_fp8(v.y, false); s[4] += p.x; s[5] += p.y;
  p = __builtin_amdgcn_cvt_pk_f32_fp8(v.y, true);  s[6] += p.x; s[7] += p.y;
}
__device__ inline unsigned char f2fp8(float v) {
  return (unsigned char)(__builtin_amdgcn_cvt_pk_fp8_f32(v, v, 0, false) & 0xff);
}
__device__ inline int wave_incl_scan_int(int v, int lane) {
#pragma unroll
  for (int off = 1; off < 64; off <<= 1) {
    int t = __shfl_up(v, off, 64);
    if (lane >= off) v += t;
  }
  return v;
}

// ------------------------- prep: weights + x->bf16/fp8 + zero bcnt ----------
__global__ __launch_bounds__(256) void prep_all(
    const float* __restrict__ W0, const float* __restrict__ W1, const float* __restrict__ W2,
    const float* __restrict__ Wm1, const float* __restrict__ Wm2,
    unsigned short* __restrict__ W0T, unsigned short* __restrict__ W1T,
    unsigned short* __restrict__ W2T, unsigned short* __restrict__ Wm1T,
    unsigned short* __restrict__ Wm2T,
    const float* __restrict__ x, unsigned short* __restrict__ xb,
    unsigned char* __restrict__ xq, int n8,
    int* __restrict__ bcnt) {
  int i = blockIdx.x * 256 + threadIdx.x;
  if (i < MAXB) bcnt[i] = 0;
  if (i < n8) {
    const float4* p = (const float4*)x;
    float4 a = p[2 * (size_t)i], b = p[2 * (size_t)i + 1];
    uint4 o;
    o.x = pack2(a.x, a.y); o.y = pack2(a.z, a.w);
    o.z = pack2(b.x, b.y); o.w = pack2(b.z, b.w);
    ((uint4*)xb)[i] = o;
    unsigned int lo = 0, hi = 0;
    lo = __builtin_amdgcn_cvt_pk_fp8_f32(a.x, a.y, lo, false);
    lo = __builtin_amdgcn_cvt_pk_fp8_f32(a.z, a.w, lo, true);
    hi = __builtin_amdgcn_cvt_pk_fp8_f32(b.x, b.y, hi, false);
    hi = __builtin_amdgcn_cvt_pk_fp8_f32(b.z, b.w, hi, true);
    uint2 q; q.x = lo; q.y = hi;
    ((uint2*)xq)[i] = q;
  }
  if (i < 49152) {                       // 3 x [128,128] -> [128n][128k]
    int w = i / 16384, r = i % 16384;
    int nn = r >> 7, k = r & 127;
    const float* W = (w == 0) ? W0 : (w == 1) ? W1 : W2;
    unsigned short* O = (w == 0) ? W0T : (w == 1) ? W1T : W2T;
    O[r] = f2bf(W[k * 128 + nn]);
  } else if (i < 49152 + 32768) {        // Wm1 [128,256] -> [256n][128k]
    int r = i - 49152;
    int nn = r >> 7, k = r & 127;
    Wm1T[r] = f2bf(Wm1[k * 256 + nn]);
  } else if (i < 49152 + 32768 + 4096) { // Wm2 [256,10] -> [16n][256k], pad 0
    int r = i - 49152 - 32768;
    int nn = r >> 8, k = r & 255;
    Wm2T[r] = (nn < 10) ? f2bf(Wm2[k * 10 + nn]) : (unsigned short)0;
  }
}

// ------------------------- bin edges into 64-node buckets -------------------
// entry = (src << 6) | (dst & 63); bucket = dst >> 6.
__global__ __launch_bounds__(256) void bin_edges(
    const int* __restrict__ src, const int* __restrict__ dst, int E, int per,
    int* __restrict__ bcnt, int* __restrict__ bucketA, int nbuckets) {
  __shared__ int hist[MAXB];
  __shared__ int base[MAXB];
  const int tid = threadIdx.x;
  const int e0 = blockIdx.x * per;
  const int e1 = (e0 + per < E) ? e0 + per : E;
  for (int j = tid; j < nbuckets; j += 256) hist[j] = 0;
  __syncthreads();
  for (int i = e0 + tid; i < e1; i += 256) atomicAdd(&hist[dst[i] >> 6], 1);
  __syncthreads();
  for (int j = tid; j < nbuckets; j += 256) {
    int h = hist[j];
    base[j] = h ? atomicAdd(&bcnt[j], h) : 0;
  }
  __syncthreads();
  for (int i = e0 + tid; i < e1; i += 256) {
    int d = dst[i], s = src[i];
    int b = d >> 6;
    int r = atomicAdd(&base[b], 1);
    bucketA[(size_t)b * BCAP + r] = (s << 6) | (d & 63);
  }
}

// ------------------------- per-bucket counting sort (once) ------------------
// Produces srcsS[b*BCAP + p] sorted by local node, boffs[b*65 + 0..64].
__global__ __launch_bounds__(256) void sort_buckets(
    const int* __restrict__ bcnt, const int* __restrict__ bucketA,
    int* __restrict__ srcsS, int* __restrict__ boffs) {
  __shared__ int rawE[BCAP];
  __shared__ int hist[64], cur[64], offs[65];
  const int tid = threadIdx.x;
  const int b = blockIdx.x;
  const int cnt = bcnt[b];
  for (int i = tid; i < cnt; i += 256) rawE[i] = bucketA[(size_t)b * BCAP + i];
  if (tid < 64) hist[tid] = 0;
  __syncthreads();
  for (int i = tid; i < cnt; i += 256) atomicAdd(&hist[rawE[i] & 63], 1);
  __syncthreads();
  if (tid < 64) {
    int v = hist[tid];
    int incl = wave_incl_scan_int(v, tid);
    offs[tid] = incl - v;
    cur[tid] = incl - v;
    if (tid == 63) offs[64] = incl;
  }
  __syncthreads();
  for (int i = tid; i < cnt; i += 256) {
    int e = rawE[i];
    int p = atomicAdd(&cur[e & 63], 1);
    srcsS[(size_t)b * BCAP + p] = e >> 6;
  }
  if (tid < 65) boffs[b * 65 + tid] = offs[tid];
}

// ------------------------- fused layer (layers 1,2) -------------------------
// Block = bucket = 64 nodes. Self term from bf16 X (streaming); neighbor
// gather from fp8 Xq (128B rows -> half the random-miss traffic).
// MFMA 64x128 (2x2 waves, wave 32m x 64n, K=128). Writes bf16 C + fp8 Cq.
__global__ __launch_bounds__(256) void fused_layer(
    const unsigned short* __restrict__ X, const unsigned char* __restrict__ Xq,
    const int* __restrict__ bcnt,
    const int* __restrict__ srcsS, const int* __restrict__ boffs,
    const unsigned short* __restrict__ BT, const float* __restrict__ bias,
    unsigned short* __restrict__ C, unsigned char* __restrict__ Cq, int M) {
  __shared__ __align__(16) unsigned short As[64 * 136];
  __shared__ int srcS[BCAP];
  __shared__ int offs[65];
  const int tid = threadIdx.x;
  const int lane = tid & 63;
  const int b = blockIdx.x;
  const int blk = b * 64;
  const int cnt = bcnt[b];

  if (tid < 65) offs[tid] = boffs[b * 65 + tid];
  for (int i = tid; i < cnt; i += 256) srcS[i] = srcsS[(size_t)b * BCAP + i];
  __syncthreads();

  // ---- gather: 4 sweeps x 16 nodes; 16 lanes; self 16B bf16, nbr 8B fp8
  const int l = tid & 15, g = tid >> 4;
  const uint4* base = (const uint4*)X;
  const uint2* baseq = (const uint2*)Xq;
#pragma unroll
  for (int s2 = 0; s2 < 4; ++s2) {
    int nl = s2 * 16 + g;
    int node = blk + nl;
    float s[8] = {0, 0, 0, 0, 0, 0, 0, 0};
    if (node < M) {
      add8(s, base[(size_t)node * 16 + l]);
      int beg = offs[nl], c = offs[nl + 1] - beg;
      int j = 0;
      for (; j + 8 <= c; j += 8) {
        int i0 = srcS[beg + j + 0], i1 = srcS[beg + j + 1];
        int i2 = srcS[beg + j + 2], i3 = srcS[beg + j + 3];
        int i4 = srcS[beg + j + 4], i5 = srcS[beg + j + 5];
        int i6 = srcS[beg + j + 6], i7 = srcS[beg + j + 7];
        uint2 v0 = baseq[(size_t)i0 * 16 + l];
        uint2 v1 = baseq[(size_t)i1 * 16 + l];
        uint2 v2 = baseq[(size_t)i2 * 16 + l];
        uint2 v3 = baseq[(size_t)i3 * 16 + l];
        uint2 v4 = baseq[(size_t)i4 * 16 + l];
        uint2 v5 = baseq[(size_t)i5 * 16 + l];
        uint2 v6 = baseq[(size_t)i6 * 16 + l];
        uint2 v7 = baseq[(size_t)i7 * 16 + l];
        addf8(s, v0); addf8(s, v1); addf8(s, v2); addf8(s, v3);
        addf8(s, v4); addf8(s, v5); addf8(s, v6); addf8(s, v7);
      }
      if (j + 4 <= c) {
        int i0 = srcS[beg + j + 0], i1 = srcS[beg + j + 1];
        int i2 = srcS[beg + j + 2], i3 = srcS[beg + j + 3];
        uint2 v0 = baseq[(size_t)i0 * 16 + l];
        uint2 v1 = baseq[(size_t)i1 * 16 + l];
        uint2 v2 = baseq[(size_t)i2 * 16 + l];
        uint2 v3 = baseq[(size_t)i3 * 16 + l];
        addf8(s, v0); addf8(s, v1); addf8(s, v2); addf8(s, v3);
        j += 4;
      }
      if (j + 2 <= c) {
        int i0 = srcS[beg + j + 0], i1 = srcS[beg + j + 1];
        uint2 v0 = baseq[(size_t)i0 * 16 + l];
        uint2 v1 = baseq[(size_t)i1 * 16 + l];
        addf8(s, v0); addf8(s, v1);
        j += 2;
      }
      if (j < c) addf8(s, baseq[(size_t)srcS[beg + j] * 16 + l]);
    }
    uint4 o;
    o.x = pack2(s[0], s[1]); o.y = pack2(s[2], s[3]);
    o.z = pack2(s[4], s[5]); o.w = pack2(s[6], s[7]);
    *(uint4*)&As[nl * 136 + l * 8] = o;
  }
  __syncthreads();

  // ---- MFMA: 4 waves 2x2; wave tile 32m x 64n; K=128
  const int w = tid >> 6;
  const int wm = w & 1, wn = w >> 1;
  const int l15 = lane & 15, quad = lane >> 4;
  const int mb = wm * 32, nb2 = wn * 64;

  const unsigned short* bp[4];
#pragma unroll
  for (int nf = 0; nf < 4; ++nf)
    bp[nf] = BT + (size_t)(nb2 + nf * 16 + l15) * 128 + quad * 8;

  v4f acc[2][4];
#pragma unroll
  for (int mf = 0; mf < 2; ++mf)
#pragma unroll
    for (int nf = 0; nf < 4; ++nf) acc[mf][nf] = (v4f)0.f;

#pragma unroll
  for (int k0 = 0; k0 < 128; k0 += 32) {
    short8 a[2], bv[4];
#pragma unroll
    for (int mf = 0; mf < 2; ++mf)
      a[mf] = *(const short8*)&As[(mb + mf * 16 + l15) * 136 + k0 + quad * 8];
#pragma unroll
    for (int nf = 0; nf < 4; ++nf) bv[nf] = *(const short8*)(bp[nf] + k0);
#pragma unroll
    for (int mf = 0; mf < 2; ++mf)
#pragma unroll
      for (int nf = 0; nf < 4; ++nf)
        acc[mf][nf] = __builtin_amdgcn_mfma_f32_16x16x32_bf16(a[mf], bv[nf], acc[mf][nf], 0, 0, 0);
  }

#pragma unroll
  for (int mf = 0; mf < 2; ++mf) {
#pragma unroll
    for (int r = 0; r < 4; ++r) {
      int grow = blk + mb + mf * 16 + quad * 4 + r;
      if (grow >= M) continue;
#pragma unroll
      for (int nf = 0; nf < 4; ++nf) {
        int gcol = nb2 + nf * 16 + l15;
        float v = fmaxf(acc[mf][nf][r] + bias[gcol], 0.f);
        C[(size_t)grow * 128 + gcol] = f2bf(v);
        Cq[(size_t)grow * 128 + gcol] = f2fp8(v);
      }
    }
  }
}

// ------------------------- fused layer 3 + MLP head -------------------------
// Same gather+MFMA as fused_layer, then head entirely in LDS:
//   t  = relu((x+agg)@W2 + b2)      -> back into As
//   Hs = relu(t @ Wm1 + bm1)        -> Hs (aliases As+srcS)
//   out= Hs @ Wm2 + bm2             (Wm2T zero-padded to 16 cols)
__global__ __launch_bounds__(256) void fused_l3_head(
    const unsigned short* __restrict__ X, const unsigned char* __restrict__ Xq,
    const int* __restrict__ bcnt,
    const int* __restrict__ srcsS, const int* __restrict__ boffs,
    const unsigned short* __restrict__ W2T, const float* __restrict__ b2,
    const unsigned short* __restrict__ Wm1T, const float* __restrict__ bm1,
    const unsigned short* __restrict__ Wm2T, const float* __restrict__ bm2,
    float* __restrict__ out, int M, int NOUT) {
  __shared__ __align__(16) unsigned char lds[64 * 264 * 2];  // Hs 33.8KB
  unsigned short* As = (unsigned short*)lds;                 // 17.4KB
  int* srcS = (int*)(lds + 64 * 136 * 2);                    // 4KB after As
  unsigned short* Hs = (unsigned short*)lds;                 // aliases both
  __shared__ int offs[65];
  const int tid = threadIdx.x;
  const int lane = tid & 63;
  const int b = blockIdx.x;
  const int blk = b * 64;
  const int cnt = bcnt[b];

  if (tid < 65) offs[tid] = boffs[b * 65 + tid];
  for (int i = tid; i < cnt; i += 256) srcS[i] = srcsS[(size_t)b * BCAP + i];
  __syncthreads();

  // ---- gather (same as fused_layer)
  const int l = tid & 15, g = tid >> 4;
  const uint4* base = (const uint4*)X;
  const uint2* baseq = (const uint2*)Xq;
#pragma unroll
  for (int s2 = 0; s2 < 4; ++s2) {
    int nl = s2 * 16 + g;
    int node = blk + nl;
    float s[8] = {0, 0, 0, 0, 0, 0, 0, 0};
    if (node < M) {
      add8(s, base[(size_t)node * 16 + l]);
      int beg = offs[nl], c = offs[nl + 1] - beg;
      int j = 0;
      for (; j + 8 <= c; j += 8) {
        int i0 = srcS[beg + j + 0], i1 = srcS[beg + j + 1];
        int i2 = srcS[beg + j + 2], i3 = srcS[beg + j + 3];
        int i4 = srcS[beg + j + 4], i5 = srcS[beg + j + 5];
        int i6 = srcS[beg + j + 6], i7 = srcS[beg + j + 7];
        uint2 v0 = baseq[(size_t)i0 * 16 + l];
        uint2 v1 = baseq[(size_t)i1 * 16 + l];
        uint2 v2 = baseq[(size_t)i2 * 16 + l];
        uint2 v3 = baseq[(size_t)i3 * 16 + l];
        uint2 v4 = baseq[(size_t)i4 * 16 + l];
        uint2 v5 = baseq[(size_t)i5 * 16 + l];
        uint2 v6 = baseq[(size_t)i6 * 16 + l];
        uint2 v7 = baseq[(size_t)i7 * 16 + l];
        addf8(s, v0); addf8(s, v1); addf8(s, v2); addf8(s, v3);
        addf8(s, v4); addf8(s, v5); addf8(s, v6); addf8(s, v7);
      }
      if (j + 4 <= c) {
        int i0 = srcS[beg + j + 0], i1 = srcS[beg + j + 1];
        int i2 = srcS[beg + j + 2], i3 = srcS[beg + j + 3];
        uint2 v0 = baseq[(size_t)i0 * 16 + l];
        uint2 v1 = baseq[(size_t)i1 * 16 + l];
        uint2 v2 = baseq[(size_t)i2 * 16 + l];
        uint2 v3 = baseq[(size_t)i3 * 16 + l];
        addf8(s, v0); addf8(s, v1); addf8(s, v2); addf8(s, v3);
        j += 4;
      }
      if (j + 2 <= c) {
        int i0 = srcS[beg + j + 0], i1 = srcS[beg + j + 1];
        uint2 v0 = baseq[(size_t)i0 * 16 + l];
        uint2 v1 = baseq[(size_t)i1 * 16 + l];
        addf8(s, v0); addf8(s, v1);
        j += 2;
      }
      if (j < c) addf8(s, baseq[(size_t)srcS[beg + j] * 16 + l]);
    }
    uint4 o;
    o.x = pack2(s[0], s[1]); o.y = pack2(s[2], s[3]);
    o.z = pack2(s[4], s[5]); o.w = pack2(s[6], s[7]);
    *(uint4*)&As[nl * 136 + l * 8] = o;
  }
  __syncthreads();

  // ---- layer-3 MFMA: 64x128, K=128
  const int w = tid >> 6;
  const int wm = w & 1, wn = w >> 1;
  const int l15 = lane & 15, quad = lane >> 4;
  const int mb = wm * 32, nb2 = wn * 64;

  v4f acc[2][4];
#pragma unroll
  for (int mf = 0; mf < 2; ++mf)
#pragma unroll
    for (int nf = 0; nf < 4; ++nf) acc[mf][nf] = (v4f)0.f;

#pragma unroll
  for (int k0 = 0; k0 < 128; k0 += 32) {
    short8 a[2], bv[4];
#pragma unroll
    for (int mf = 0; mf < 2; ++mf)
      a[mf] = *(const short8*)&As[(mb + mf * 16 + l15) * 136 + k0 + quad * 8];
#pragma unroll
    for (int nf = 0; nf < 4; ++nf)
      bv[nf] = *(const short8*)(W2T + (size_t)(nb2 + nf * 16 + l15) * 128 + quad * 8 + k0);
#pragma unroll
    for (int mf = 0; mf < 2; ++mf)
#pragma unroll
      for (int nf = 0; nf < 4; ++nf)
        acc[mf][nf] = __builtin_amdgcn_mfma_f32_16x16x32_bf16(a[mf], bv[nf], acc[mf][nf], 0, 0, 0);
  }
  __syncthreads();  // all As reads done before rewrite

  // t = relu(acc + b2) -> back into As (local rows 0..63, cols 0..127)
#pragma unroll
  for (int mf = 0; mf < 2; ++mf)
#pragma unroll
    for (int r = 0; r < 4; ++r) {
      int row = mb + mf * 16 + quad * 4 + r;
#pragma unroll
      for (int nf = 0; nf < 4; ++nf) {
        int col = nb2 + nf * 16 + l15;
        As[row * 136 + col] = f2bf(fmaxf(acc[mf][nf][r] + b2[col], 0.f));
      }
    }
  __syncthreads();

  // ---- head phase A: Hm = relu(t @ Wm1 + bm1), 64x256, K=128
  const int nbH = wn * 128;
  v4f acc2[2][8];
#pragma unroll
  for (int mf = 0; mf < 2; ++mf)
#pragma unroll
    for (int nf = 0; nf < 8; ++nf) acc2[mf][nf] = (v4f)0.f;

#pragma unroll
  for (int k0 = 0; k0 < 128; k0 += 32) {
    short8 a[2];
#pragma unroll
    for (int mf = 0; mf < 2; ++mf)
      a[mf] = *(const short8*)&As[(mb + mf * 16 + l15) * 136 + k0 + quad * 8];
#pragma unroll
    for (int nf = 0; nf < 8; ++nf) {
      short8 bb = *(const short8*)(Wm1T + (size_t)(nbH + nf * 16 + l15) * 128 + quad * 8 + k0);
#pragma unroll
      for (int mf = 0; mf < 2; ++mf)
        acc2[mf][nf] = __builtin_amdgcn_mfma_f32_16x16x32_bf16(a[mf], bb, acc2[mf][nf], 0, 0, 0);
    }
  }
  __syncthreads();  // As reads done; Hs may overwrite

#pragma unroll
  for (int mf = 0; mf < 2; ++mf)
#pragma unroll
    for (int r = 0; r < 4; ++r) {
      int row = mb + mf * 16 + quad * 4 + r;
#pragma unroll
      for (int nf = 0; nf < 8; ++nf) {
        int col = nbH + nf * 16 + l15;
        Hs[row * 264 + col] = f2bf(fmaxf(acc2[mf][nf][r] + bm1[col], 0.f));
      }
    }
  __syncthreads();

  // ---- head phase B: out = Hs @ Wm2 + bm2; 64x16, K=256; wave = 16 rows
  const int rowl = w * 16 + l15;
  const unsigned short* bp2 = Wm2T + (size_t)l15 * 256 + quad * 8;
  v4f acc3 = (v4f)0.f;
#pragma unroll
  for (int k0 = 0; k0 < 256; k0 += 32)
    acc3 = __builtin_amdgcn_mfma_f32_16x16x32_bf16(
        *(const short8*)&Hs[rowl * 264 + k0 + quad * 8],
        *(const short8*)(bp2 + k0), acc3, 0, 0, 0);
  float bb = (l15 < NOUT) ? bm2[l15] : 0.f;
#pragma unroll
  for (int r = 0; r < 4; ++r) {
    int grow = blk + w * 16 + quad * 4 + r;
    if (grow < M && l15 < NOUT) out[(size_t)grow * NOUT + l15] = acc3[r] + bb;
  }
}

// ---------------------------------------------------------------------------

extern "C" void kernel_launch(void* const* d_in, const int* in_sizes, int n_in,
                              void* d_out, int out_size, void* d_ws, size_t ws_size,
                              hipStream_t stream) {
  const float* x   = (const float*)d_in[0];
  const int*   ei  = (const int*)d_in[1];
  const float* W0  = (const float*)d_in[2];
  const float* b0  = (const float*)d_in[3];
  const float* W1  = (const float*)d_in[4];
  const float* b1  = (const float*)d_in[5];
  const float* W2  = (const float*)d_in[6];
  const float* b2  = (const float*)d_in[7];
  const float* Wm1 = (const float*)d_in[8];
  const float* bm1 = (const float*)d_in[9];
  const float* Wm2 = (const float*)d_in[10];
  const float* bm2 = (const float*)d_in[11];
  float* out = (float*)d_out;

  const int D = 128;
  const int N = in_sizes[0] / D;   // 50000
  const int E = in_sizes[1] / 2;   // 600000
  const int L = in_sizes[11];      // 10
  const int nb = (N + 63) / 64;    // 782 buckets == layer tiles

  const int* srcv = ei;
  const int* dstv = ei + E;

  char* ws = (char*)d_ws;
  size_t off = 0;
  auto alloc = [&](size_t bytes) -> void* {
    void* p = ws + off;
    off = (off + bytes + 255) & ~(size_t)255;
    return p;
  };
  int* bcnt    = (int*)alloc((size_t)MAXB * 4);
  int* bucketA = (int*)alloc((size_t)nb * BCAP * 4);
  int* srcsS   = (int*)alloc((size_t)nb * BCAP * 4);
  int* boffs   = (int*)alloc((size_t)nb * 65 * 4);
  unsigned short* xb   = (unsigned short*)alloc((size_t)N * 128 * 2);
  unsigned short* h1   = (unsigned short*)alloc((size_t)N * 128 * 2);
  unsigned short* h2   = (unsigned short*)alloc((size_t)N * 128 * 2);
  unsigned char*  xq   = (unsigned char*)alloc((size_t)N * 128);
  unsigned char*  h1q  = (unsigned char*)alloc((size_t)N * 128);
  unsigned char*  h2q  = (unsigned char*)alloc((size_t)N * 128);
  unsigned short* W0T  = (unsigned short*)alloc(128 * 128 * 2);
  unsigned short* W1T  = (unsigned short*)alloc(128 * 128 * 2);
  unsigned short* W2T  = (unsigned short*)alloc(128 * 128 * 2);
  unsigned short* Wm1T = (unsigned short*)alloc(256 * 128 * 2);
  unsigned short* Wm2T = (unsigned short*)alloc(16 * 256 * 2);
  (void)ws_size; (void)n_in; (void)out_size;

  const int tpb = 256;
  int n8 = N * 16;
  prep_all<<<dim3((n8 + tpb - 1) / tpb), dim3(tpb), 0, stream>>>(
      W0, W1, W2, Wm1, Wm2, W0T, W1T, W2T, Wm1T, Wm2T, x, xb, xq, n8, bcnt);

  const int nbin = 256;
  int per = (E + nbin - 1) / nbin;
  bin_edges<<<dim3(nbin), dim3(tpb), 0, stream>>>(srcv, dstv, E, per, bcnt, bucketA, nb);
  sort_buckets<<<dim3(nb), dim3(tpb), 0, stream>>>(bcnt, bucketA, srcsS, boffs);

  dim3 lgrid(nb);
  fused_layer<<<lgrid, dim3(tpb), 0, stream>>>(xb, xq, bcnt, srcsS, boffs, W0T, b0, h1, h1q, N);
  fused_layer<<<lgrid, dim3(tpb), 0, stream>>>(h1, h1q, bcnt, srcsS, boffs, W1T, b1, h2, h2q, N);
  fused_l3_head<<<lgrid, dim3(tpb), 0, stream>>>(h2, h2q, bcnt, srcsS, boffs, W2T, b2,
                                                 Wm1T, bm1, Wm2T, bm2, out, N, L);
}

// Round 3
// 224.881 us; speedup vs baseline: 1.1194x; 1.0317x over previous
//
#include <hip/hip_runtime.h>

// ---------------------------------------------------------------------------
// GIN: 3 x (bucket gather-sum + (x+agg)@W + b, relu) + MLP head, bf16 MFMA.
// r9: dwordx4 fp8 gather -> 8 lanes/edge (was 16), one wave instr covers
//     8 edges (was 4). Evidence r6/r7/r8: time invariant to waves (2x),
//     miss bytes (1/2), miss requests (1/2) -- but proportional to the
//     ~150k scattered vmem instructions + per-thread dependent-batch
//     chains. This halves both. Decode VALU total unchanged.
//     6 dispatches: prep_all, bin_edges, sort_buckets, 2x fused_layer,
//     fused_l3_head.
// ---------------------------------------------------------------------------

typedef short short8 __attribute__((ext_vector_type(8)));
typedef float v4f __attribute__((ext_vector_type(4)));
typedef float v2f __attribute__((ext_vector_type(2)));

#define BCAP 1024   // bucket capacity: avg 768 edges, +9 sigma head-room
#define MAXB 1024   // >= nbuckets (782)

__device__ inline unsigned short f2bf(float f) {
  union { float f; unsigned int u; } c; c.f = f;
  unsigned int u = c.u;
  return (unsigned short)((u + 0x7fffu + ((u >> 16) & 1u)) >> 16);  // RNE
}
__device__ inline float bfbits2f(unsigned int hi) {
  union { unsigned int u; float f; } c; c.u = hi; return c.f;
}
__device__ inline unsigned int pack2(float a, float b) {
  return (unsigned int)f2bf(a) | ((unsigned int)f2bf(b) << 16);
}
__device__ inline void add8(float* s, uint4 v) {
  s[0] += bfbits2f(v.x << 16); s[1] += bfbits2f(v.x & 0xffff0000u);
  s[2] += bfbits2f(v.y << 16); s[3] += bfbits2f(v.y & 0xffff0000u);
  s[4] += bfbits2f(v.z << 16); s[5] += bfbits2f(v.z & 0xffff0000u);
  s[6] += bfbits2f(v.w << 16); s[7] += bfbits2f(v.w & 0xffff0000u);
}
// decode 16 fp8 (e4m3, HW format) and accumulate into s[0..15]
__device__ inline void addf8q(float* s, uint4 v) {
  v2f p;
  p = __builtin_amdgcn_cvt_pk_f32_fp8(v.x, false); s[0]  += p.x; s[1]  += p.y;
  p = __builtin_amdgcn_cvt_pk_f32_fp8(v.x, true);  s[2]  += p.x; s[3]  += p.y;
  p = __builtin_amdgcn_cvt_pk_f32_fp8(v.y, false); s[4]  += p.x; s[5]  += p.y;
  p = __builtin_amdgcn_cvt_pk_f32_fp8(v.y, true);  s[6]  += p.x; s[7]  += p.y;
  p = __builtin_amdgcn_cvt_pk_f32_fp8(v.z, false); s[8]  += p.x; s[9]  += p.y;
  p = __builtin_amdgcn_cvt_pk_f32_fp8(v.z, true);  s[10] += p.x; s[11] += p.y;
  p = __builtin_amdgcn_cvt_pk_f32_fp8(v.w, false); s[12] += p.x; s[13] += p.y;
  p = __builtin_amdgcn_cvt_pk_f32_fp8(v.w, true);  s[14] += p.x; s[15] += p.y;
}
__device__ inline unsigned char f2fp8(float v) {
  return (unsigned char)(__builtin_amdgcn_cvt_pk_fp8_f32(v, v, 0, false) & 0xff);
}
__device__ inline int wave_incl_scan_int(int v, int lane) {
#pragma unroll
  for (int off = 1; off < 64; off <<= 1) {
    int t = __shfl_up(v, off, 64);
    if (lane >= off) v += t;
  }
  return v;
}

// ------------------------- prep: weights + x->bf16/fp8 + zero bcnt ----------
__global__ __launch_bounds__(256) void prep_all(
    const float* __restrict__ W0, const float* __restrict__ W1, const float* __restrict__ W2,
    const float* __restrict__ Wm1, const float* __restrict__ Wm2,
    unsigned short* __restrict__ W0T, unsigned short* __restrict__ W1T,
    unsigned short* __restrict__ W2T, unsigned short* __restrict__ Wm1T,
    unsigned short* __restrict__ Wm2T,
    const float* __restrict__ x, unsigned short* __restrict__ xb,
    unsigned char* __restrict__ xq, int n8,
    int* __restrict__ bcnt) {
  int i = blockIdx.x * 256 + threadIdx.x;
  if (i < MAXB) bcnt[i] = 0;
  if (i < n8) {
    const float4* p = (const float4*)x;
    float4 a = p[2 * (size_t)i], b = p[2 * (size_t)i + 1];
    uint4 o;
    o.x = pack2(a.x, a.y); o.y = pack2(a.z, a.w);
    o.z = pack2(b.x, b.y); o.w = pack2(b.z, b.w);
    ((uint4*)xb)[i] = o;
    unsigned int lo = 0, hi = 0;
    lo = __builtin_amdgcn_cvt_pk_fp8_f32(a.x, a.y, lo, false);
    lo = __builtin_amdgcn_cvt_pk_fp8_f32(a.z, a.w, lo, true);
    hi = __builtin_amdgcn_cvt_pk_fp8_f32(b.x, b.y, hi, false);
    hi = __builtin_amdgcn_cvt_pk_fp8_f32(b.z, b.w, hi, true);
    uint2 q; q.x = lo; q.y = hi;
    ((uint2*)xq)[i] = q;
  }
  if (i < 49152) {                       // 3 x [128,128] -> [128n][128k]
    int w = i / 16384, r = i % 16384;
    int nn = r >> 7, k = r & 127;
    const float* W = (w == 0) ? W0 : (w == 1) ? W1 : W2;
    unsigned short* O = (w == 0) ? W0T : (w == 1) ? W1T : W2T;
    O[r] = f2bf(W[k * 128 + nn]);
  } else if (i < 49152 + 32768) {        // Wm1 [128,256] -> [256n][128k]
    int r = i - 49152;
    int nn = r >> 7, k = r & 127;
    Wm1T[r] = f2bf(Wm1[k * 256 + nn]);
  } else if (i < 49152 + 32768 + 4096) { // Wm2 [256,10] -> [16n][256k], pad 0
    int r = i - 49152 - 32768;
    int nn = r >> 8, k = r & 255;
    Wm2T[r] = (nn < 10) ? f2bf(Wm2[k * 10 + nn]) : (unsigned short)0;
  }
}

// ------------------------- bin edges into 64-node buckets -------------------
// entry = (src << 6) | (dst & 63); bucket = dst >> 6.
__global__ __launch_bounds__(256) void bin_edges(
    const int* __restrict__ src, const int* __restrict__ dst, int E, int per,
    int* __restrict__ bcnt, int* __restrict__ bucketA, int nbuckets) {
  __shared__ int hist[MAXB];
  __shared__ int base[MAXB];
  const int tid = threadIdx.x;
  const int e0 = blockIdx.x * per;
  const int e1 = (e0 + per < E) ? e0 + per : E;
  for (int j = tid; j < nbuckets; j += 256) hist[j] = 0;
  __syncthreads();
  for (int i = e0 + tid; i < e1; i += 256) atomicAdd(&hist[dst[i] >> 6], 1);
  __syncthreads();
  for (int j = tid; j < nbuckets; j += 256) {
    int h = hist[j];
    base[j] = h ? atomicAdd(&bcnt[j], h) : 0;
  }
  __syncthreads();
  for (int i = e0 + tid; i < e1; i += 256) {
    int d = dst[i], s = src[i];
    int b = d >> 6;
    int r = atomicAdd(&base[b], 1);
    bucketA[(size_t)b * BCAP + r] = (s << 6) | (d & 63);
  }
}

// ------------------------- per-bucket counting sort (once) ------------------
// Produces srcsS[b*BCAP + p] sorted by local node, boffs[b*65 + 0..64].
__global__ __launch_bounds__(256) void sort_buckets(
    const int* __restrict__ bcnt, const int* __restrict__ bucketA,
    int* __restrict__ srcsS, int* __restrict__ boffs) {
  __shared__ int rawE[BCAP];
  __shared__ int hist[64], cur[64], offs[65];
  const int tid = threadIdx.x;
  const int b = blockIdx.x;
  const int cnt = bcnt[b];
  for (int i = tid; i < cnt; i += 256) rawE[i] = bucketA[(size_t)b * BCAP + i];
  if (tid < 64) hist[tid] = 0;
  __syncthreads();
  for (int i = tid; i < cnt; i += 256) atomicAdd(&hist[rawE[i] & 63], 1);
  __syncthreads();
  if (tid < 64) {
    int v = hist[tid];
    int incl = wave_incl_scan_int(v, tid);
    offs[tid] = incl - v;
    cur[tid] = incl - v;
    if (tid == 63) offs[64] = incl;
  }
  __syncthreads();
  for (int i = tid; i < cnt; i += 256) {
    int e = rawE[i];
    int p = atomicAdd(&cur[e & 63], 1);
    srcsS[(size_t)b * BCAP + p] = e >> 6;
  }
  if (tid < 65) boffs[b * 65 + tid] = offs[tid];
}

// ------------------------- fused layer (layers 1,2) -------------------------
// Block = bucket = 64 nodes. Self term from bf16 X (streaming); neighbor
// gather from fp8 Xq via dwordx4: 8 lanes x 16B cover a 128B row, so one
// wave instr gathers 8 edges. 2 sweeps x 32 nodes. NO barriers in gather.
// MFMA 64x128 (2x2 waves, wave 32m x 64n, K=128). Writes bf16 C + fp8 Cq.
__global__ __launch_bounds__(256) void fused_layer(
    const unsigned short* __restrict__ X, const unsigned char* __restrict__ Xq,
    const int* __restrict__ bcnt,
    const int* __restrict__ srcsS, const int* __restrict__ boffs,
    const unsigned short* __restrict__ BT, const float* __restrict__ bias,
    unsigned short* __restrict__ C, unsigned char* __restrict__ Cq, int M) {
  __shared__ __align__(16) unsigned short As[64 * 136];
  __shared__ int srcS[BCAP];
  __shared__ int offs[65];
  const int tid = threadIdx.x;
  const int lane = tid & 63;
  const int b = blockIdx.x;
  const int blk = b * 64;
  const int cnt = bcnt[b];

  if (tid < 65) offs[tid] = boffs[b * 65 + tid];
  for (int i = tid; i < cnt; i += 256) srcS[i] = srcsS[(size_t)b * BCAP + i];
  __syncthreads();

  // ---- gather: 2 sweeps x 32 nodes; 8 lanes x 16B fp8 per row
  const int l = tid & 7, g = tid >> 3;
  const uint4* base = (const uint4*)X;    // bf16 rows: 16 x uint4
  const uint4* baseq = (const uint4*)Xq;  // fp8 rows:   8 x uint4
#pragma unroll
  for (int s2 = 0; s2 < 2; ++s2) {
    int nl = s2 * 32 + g;
    int node = blk + nl;
    float s[16] = {0, 0, 0, 0, 0, 0, 0, 0, 0, 0, 0, 0, 0, 0, 0, 0};
    if (node < M) {
      add8(s, base[(size_t)node * 16 + l * 2]);
      add8(s + 8, base[(size_t)node * 16 + l * 2 + 1]);
      int beg = offs[nl], c = offs[nl + 1] - beg;
      int j = 0;
      for (; j + 8 <= c; j += 8) {
        int i0 = srcS[beg + j + 0], i1 = srcS[beg + j + 1];
        int i2 = srcS[beg + j + 2], i3 = srcS[beg + j + 3];
        int i4 = srcS[beg + j + 4], i5 = srcS[beg + j + 5];
        int i6 = srcS[beg + j + 6], i7 = srcS[beg + j + 7];
        uint4 v0 = baseq[(size_t)i0 * 8 + l];
        uint4 v1 = baseq[(size_t)i1 * 8 + l];
        uint4 v2 = baseq[(size_t)i2 * 8 + l];
        uint4 v3 = baseq[(size_t)i3 * 8 + l];
        uint4 v4 = baseq[(size_t)i4 * 8 + l];
        uint4 v5 = baseq[(size_t)i5 * 8 + l];
        uint4 v6 = baseq[(size_t)i6 * 8 + l];
        uint4 v7 = baseq[(size_t)i7 * 8 + l];
        addf8q(s, v0); addf8q(s, v1); addf8q(s, v2); addf8q(s, v3);
        addf8q(s, v4); addf8q(s, v5); addf8q(s, v6); addf8q(s, v7);
      }
      if (j + 4 <= c) {
        int i0 = srcS[beg + j + 0], i1 = srcS[beg + j + 1];
        int i2 = srcS[beg + j + 2], i3 = srcS[beg + j + 3];
        uint4 v0 = baseq[(size_t)i0 * 8 + l];
        uint4 v1 = baseq[(size_t)i1 * 8 + l];
        uint4 v2 = baseq[(size_t)i2 * 8 + l];
        uint4 v3 = baseq[(size_t)i3 * 8 + l];
        addf8q(s, v0); addf8q(s, v1); addf8q(s, v2); addf8q(s, v3);
        j += 4;
      }
      if (j + 2 <= c) {
        int i0 = srcS[beg + j + 0], i1 = srcS[beg + j + 1];
        uint4 v0 = baseq[(size_t)i0 * 8 + l];
        uint4 v1 = baseq[(size_t)i1 * 8 + l];
        addf8q(s, v0); addf8q(s, v1);
        j += 2;
      }
      if (j < c) addf8q(s, baseq[(size_t)srcS[beg + j] * 8 + l]);
    }
    uint4 o0, o1;
    o0.x = pack2(s[0], s[1]);   o0.y = pack2(s[2], s[3]);
    o0.z = pack2(s[4], s[5]);   o0.w = pack2(s[6], s[7]);
    o1.x = pack2(s[8], s[9]);   o1.y = pack2(s[10], s[11]);
    o1.z = pack2(s[12], s[13]); o1.w = pack2(s[14], s[15]);
    *(uint4*)&As[nl * 136 + l * 16] = o0;
    *(uint4*)&As[nl * 136 + l * 16 + 8] = o1;
  }
  __syncthreads();

  // ---- MFMA: 4 waves 2x2; wave tile 32m x 64n; K=128
  const int w = tid >> 6;
  const int wm = w & 1, wn = w >> 1;
  const int l15 = lane & 15, quad = lane >> 4;
  const int mb = wm * 32, nb2 = wn * 64;

  const unsigned short* bp[4];
#pragma unroll
  for (int nf = 0; nf < 4; ++nf)
    bp[nf] = BT + (size_t)(nb2 + nf * 16 + l15) * 128 + quad * 8;

  v4f acc[2][4];
#pragma unroll
  for (int mf = 0; mf < 2; ++mf)
#pragma unroll
    for (int nf = 0; nf < 4; ++nf) acc[mf][nf] = (v4f)0.f;

#pragma unroll
  for (int k0 = 0; k0 < 128; k0 += 32) {
    short8 a[2], bv[4];
#pragma unroll
    for (int mf = 0; mf < 2; ++mf)
      a[mf] = *(const short8*)&As[(mb + mf * 16 + l15) * 136 + k0 + quad * 8];
#pragma unroll
    for (int nf = 0; nf < 4; ++nf) bv[nf] = *(const short8*)(bp[nf] + k0);
#pragma unroll
    for (int mf = 0; mf < 2; ++mf)
#pragma unroll
      for (int nf = 0; nf < 4; ++nf)
        acc[mf][nf] = __builtin_amdgcn_mfma_f32_16x16x32_bf16(a[mf], bv[nf], acc[mf][nf], 0, 0, 0);
  }

#pragma unroll
  for (int mf = 0; mf < 2; ++mf) {
#pragma unroll
    for (int r = 0; r < 4; ++r) {
      int grow = blk + mb + mf * 16 + quad * 4 + r;
      if (grow >= M) continue;
#pragma unroll
      for (int nf = 0; nf < 4; ++nf) {
        int gcol = nb2 + nf * 16 + l15;
        float v = fmaxf(acc[mf][nf][r] + bias[gcol], 0.f);
        C[(size_t)grow * 128 + gcol] = f2bf(v);
        Cq[(size_t)grow * 128 + gcol] = f2fp8(v);
      }
    }
  }
}

// ------------------------- fused layer 3 + MLP head -------------------------
// Same gather+MFMA as fused_layer, then head entirely in LDS:
//   t  = relu((x+agg)@W2 + b2)      -> back into As
//   Hs = relu(t @ Wm1 + bm1)        -> Hs (aliases As+srcS)
//   out= Hs @ Wm2 + bm2             (Wm2T zero-padded to 16 cols)
__global__ __launch_bounds__(256) void fused_l3_head(
    const unsigned short* __restrict__ X, const unsigned char* __restrict__ Xq,
    const int* __restrict__ bcnt,
    const int* __restrict__ srcsS, const int* __restrict__ boffs,
    const unsigned short* __restrict__ W2T, const float* __restrict__ b2,
    const unsigned short* __restrict__ Wm1T, const float* __restrict__ bm1,
    const unsigned short* __restrict__ Wm2T, const float* __restrict__ bm2,
    float* __restrict__ out, int M, int NOUT) {
  __shared__ __align__(16) unsigned char lds[64 * 264 * 2];  // Hs 33.8KB
  unsigned short* As = (unsigned short*)lds;                 // 17.4KB
  int* srcS = (int*)(lds + 64 * 136 * 2);                    // 4KB after As
  unsigned short* Hs = (unsigned short*)lds;                 // aliases both
  __shared__ int offs[65];
  const int tid = threadIdx.x;
  const int lane = tid & 63;
  const int b = blockIdx.x;
  const int blk = b * 64;
  const int cnt = bcnt[b];

  if (tid < 65) offs[tid] = boffs[b * 65 + tid];
  for (int i = tid; i < cnt; i += 256) srcS[i] = srcsS[(size_t)b * BCAP + i];
  __syncthreads();

  // ---- gather (same as fused_layer)
  const int l = tid & 7, g = tid >> 3;
  const uint4* base = (const uint4*)X;
  const uint4* baseq = (const uint4*)Xq;
#pragma unroll
  for (int s2 = 0; s2 < 2; ++s2) {
    int nl = s2 * 32 + g;
    int node = blk + nl;
    float s[16] = {0, 0, 0, 0, 0, 0, 0, 0, 0, 0, 0, 0, 0, 0, 0, 0};
    if (node < M) {
      add8(s, base[(size_t)node * 16 + l * 2]);
      add8(s + 8, base[(size_t)node * 16 + l * 2 + 1]);
      int beg = offs[nl], c = offs[nl + 1] - beg;
      int j = 0;
      for (; j + 8 <= c; j += 8) {
        int i0 = srcS[beg + j + 0], i1 = srcS[beg + j + 1];
        int i2 = srcS[beg + j + 2], i3 = srcS[beg + j + 3];
        int i4 = srcS[beg + j + 4], i5 = srcS[beg + j + 5];
        int i6 = srcS[beg + j + 6], i7 = srcS[beg + j + 7];
        uint4 v0 = baseq[(size_t)i0 * 8 + l];
        uint4 v1 = baseq[(size_t)i1 * 8 + l];
        uint4 v2 = baseq[(size_t)i2 * 8 + l];
        uint4 v3 = baseq[(size_t)i3 * 8 + l];
        uint4 v4 = baseq[(size_t)i4 * 8 + l];
        uint4 v5 = baseq[(size_t)i5 * 8 + l];
        uint4 v6 = baseq[(size_t)i6 * 8 + l];
        uint4 v7 = baseq[(size_t)i7 * 8 + l];
        addf8q(s, v0); addf8q(s, v1); addf8q(s, v2); addf8q(s, v3);
        addf8q(s, v4); addf8q(s, v5); addf8q(s, v6); addf8q(s, v7);
      }
      if (j + 4 <= c) {
        int i0 = srcS[beg + j + 0], i1 = srcS[beg + j + 1];
        int i2 = srcS[beg + j + 2], i3 = srcS[beg + j + 3];
        uint4 v0 = baseq[(size_t)i0 * 8 + l];
        uint4 v1 = baseq[(size_t)i1 * 8 + l];
        uint4 v2 = baseq[(size_t)i2 * 8 + l];
        uint4 v3 = baseq[(size_t)i3 * 8 + l];
        addf8q(s, v0); addf8q(s, v1); addf8q(s, v2); addf8q(s, v3);
        j += 4;
      }
      if (j + 2 <= c) {
        int i0 = srcS[beg + j + 0], i1 = srcS[beg + j + 1];
        uint4 v0 = baseq[(size_t)i0 * 8 + l];
        uint4 v1 = baseq[(size_t)i1 * 8 + l];
        addf8q(s, v0); addf8q(s, v1);
        j += 2;
      }
      if (j < c) addf8q(s, baseq[(size_t)srcS[beg + j] * 8 + l]);
    }
    uint4 o0, o1;
    o0.x = pack2(s[0], s[1]);   o0.y = pack2(s[2], s[3]);
    o0.z = pack2(s[4], s[5]);   o0.w = pack2(s[6], s[7]);
    o1.x = pack2(s[8], s[9]);   o1.y = pack2(s[10], s[11]);
    o1.z = pack2(s[12], s[13]); o1.w = pack2(s[14], s[15]);
    *(uint4*)&As[nl * 136 + l * 16] = o0;
    *(uint4*)&As[nl * 136 + l * 16 + 8] = o1;
  }
  __syncthreads();

  // ---- layer-3 MFMA: 64x128, K=128
  const int w = tid >> 6;
  const int wm = w & 1, wn = w >> 1;
  const int l15 = lane & 15, quad = lane >> 4;
  const int mb = wm * 32, nb2 = wn * 64;

  v4f acc[2][4];
#pragma unroll
  for (int mf = 0; mf < 2; ++mf)
#pragma unroll
    for (int nf = 0; nf < 4; ++nf) acc[mf][nf] = (v4f)0.f;

#pragma unroll
  for (int k0 = 0; k0 < 128; k0 += 32) {
    short8 a[2], bv[4];
#pragma unroll
    for (int mf = 0; mf < 2; ++mf)
      a[mf] = *(const short8*)&As[(mb + mf * 16 + l15) * 136 + k0 + quad * 8];
#pragma unroll
    for (int nf = 0; nf < 4; ++nf)
      bv[nf] = *(const short8*)(W2T + (size_t)(nb2 + nf * 16 + l15) * 128 + quad * 8 + k0);
#pragma unroll
    for (int mf = 0; mf < 2; ++mf)
#pragma unroll
      for (int nf = 0; nf < 4; ++nf)
        acc[mf][nf] = __builtin_amdgcn_mfma_f32_16x16x32_bf16(a[mf], bv[nf], acc[mf][nf], 0, 0, 0);
  }
  __syncthreads();  // all As reads done before rewrite

  // t = relu(acc + b2) -> back into As (local rows 0..63, cols 0..127)
#pragma unroll
  for (int mf = 0; mf < 2; ++mf)
#pragma unroll
    for (int r = 0; r < 4; ++r) {
      int row = mb + mf * 16 + quad * 4 + r;
#pragma unroll
      for (int nf = 0; nf < 4; ++nf) {
        int col = nb2 + nf * 16 + l15;
        As[row * 136 + col] = f2bf(fmaxf(acc[mf][nf][r] + b2[col], 0.f));
      }
    }
  __syncthreads();

  // ---- head phase A: Hm = relu(t @ Wm1 + bm1), 64x256, K=128
  const int nbH = wn * 128;
  v4f acc2[2][8];
#pragma unroll
  for (int mf = 0; mf < 2; ++mf)
#pragma unroll
    for (int nf = 0; nf < 8; ++nf) acc2[mf][nf] = (v4f)0.f;

#pragma unroll
  for (int k0 = 0; k0 < 128; k0 += 32) {
    short8 a[2];
#pragma unroll
    for (int mf = 0; mf < 2; ++mf)
      a[mf] = *(const short8*)&As[(mb + mf * 16 + l15) * 136 + k0 + quad * 8];
#pragma unroll
    for (int nf = 0; nf < 8; ++nf) {
      short8 bb = *(const short8*)(Wm1T + (size_t)(nbH + nf * 16 + l15) * 128 + quad * 8 + k0);
#pragma unroll
      for (int mf = 0; mf < 2; ++mf)
        acc2[mf][nf] = __builtin_amdgcn_mfma_f32_16x16x32_bf16(a[mf], bb, acc2[mf][nf], 0, 0, 0);
    }
  }
  __syncthreads();  // As reads done; Hs may overwrite

#pragma unroll
  for (int mf = 0; mf < 2; ++mf)
#pragma unroll
    for (int r = 0; r < 4; ++r) {
      int row = mb + mf * 16 + quad * 4 + r;
#pragma unroll
      for (int nf = 0; nf < 8; ++nf) {
        int col = nbH + nf * 16 + l15;
        Hs[row * 264 + col] = f2bf(fmaxf(acc2[mf][nf][r] + bm1[col], 0.f));
      }
    }
  __syncthreads();

  // ---- head phase B: out = Hs @ Wm2 + bm2; 64x16, K=256; wave = 16 rows
  const int rowl = w * 16 + l15;
  const unsigned short* bp2 = Wm2T + (size_t)l15 * 256 + quad * 8;
  v4f acc3 = (v4f)0.f;
#pragma unroll
  for (int k0 = 0; k0 < 256; k0 += 32)
    acc3 = __builtin_amdgcn_mfma_f32_16x16x32_bf16(
        *(const short8*)&Hs[rowl * 264 + k0 + quad * 8],
        *(const short8*)(bp2 + k0), acc3, 0, 0, 0);
  float bb = (l15 < NOUT) ? bm2[l15] : 0.f;
#pragma unroll
  for (int r = 0; r < 4; ++r) {
    int grow = blk + w * 16 + quad * 4 + r;
    if (grow < M && l15 < NOUT) out[(size_t)grow * NOUT + l15] = acc3[r] + bb;
  }
}

// ---------------------------------------------------------------------------

extern "C" void kernel_launch(void* const* d_in, const int* in_sizes, int n_in,
                              void* d_out, int out_size, void* d_ws, size_t ws_size,
                              hipStream_t stream) {
  const float* x   = (const float*)d_in[0];
  const int*   ei  = (const int*)d_in[1];
  const float* W0  = (const float*)d_in[2];
  const float* b0  = (const float*)d_in[3];
  const float* W1  = (const float*)d_in[4];
  const float* b1  = (const float*)d_in[5];
  const float* W2  = (const float*)d_in[6];
  const float* b2  = (const float*)d_in[7];
  const float* Wm1 = (const float*)d_in[8];
  const float* bm1 = (const float*)d_in[9];
  const float* Wm2 = (const float*)d_in[10];
  const float* bm2 = (const float*)d_in[11];
  float* out = (float*)d_out;

  const int D = 128;
  const int N = in_sizes[0] / D;   // 50000
  const int E = in_sizes[1] / 2;   // 600000
  const int L = in_sizes[11];      // 10
  const int nb = (N + 63) / 64;    // 782 buckets == layer tiles

  const int* srcv = ei;
  const int* dstv = ei + E;

  char* ws = (char*)d_ws;
  size_t off = 0;
  auto alloc = [&](size_t bytes) -> void* {
    void* p = ws + off;
    off = (off + bytes + 255) & ~(size_t)255;
    return p;
  };
  int* bcnt    = (int*)alloc((size_t)MAXB * 4);
  int* bucketA = (int*)alloc((size_t)nb * BCAP * 4);
  int* srcsS   = (int*)alloc((size_t)nb * BCAP * 4);
  int* boffs   = (int*)alloc((size_t)nb * 65 * 4);
  unsigned short* xb   = (unsigned short*)alloc((size_t)N * 128 * 2);
  unsigned short* h1   = (unsigned short*)alloc((size_t)N * 128 * 2);
  unsigned short* h2   = (unsigned short*)alloc((size_t)N * 128 * 2);
  unsigned char*  xq   = (unsigned char*)alloc((size_t)N * 128);
  unsigned char*  h1q  = (unsigned char*)alloc((size_t)N * 128);
  unsigned char*  h2q  = (unsigned char*)alloc((size_t)N * 128);
  unsigned short* W0T  = (unsigned short*)alloc(128 * 128 * 2);
  unsigned short* W1T  = (unsigned short*)alloc(128 * 128 * 2);
  unsigned short* W2T  = (unsigned short*)alloc(128 * 128 * 2);
  unsigned short* Wm1T = (unsigned short*)alloc(256 * 128 * 2);
  unsigned short* Wm2T = (unsigned short*)alloc(16 * 256 * 2);
  (void)ws_size; (void)n_in; (void)out_size;

  const int tpb = 256;
  int n8 = N * 16;
  prep_all<<<dim3((n8 + tpb - 1) / tpb), dim3(tpb), 0, stream>>>(
      W0, W1, W2, Wm1, Wm2, W0T, W1T, W2T, Wm1T, Wm2T, x, xb, xq, n8, bcnt);

  const int nbin = 256;
  int per = (E + nbin - 1) / nbin;
  bin_edges<<<dim3(nbin), dim3(tpb), 0, stream>>>(srcv, dstv, E, per, bcnt, bucketA, nb);
  sort_buckets<<<dim3(nb), dim3(tpb), 0, stream>>>(bcnt, bucketA, srcsS, boffs);

  dim3 lgrid(nb);
  fused_layer<<<lgrid, dim3(tpb), 0, stream>>>(xb, xq, bcnt, srcsS, boffs, W0T, b0, h1, h1q, N);
  fused_layer<<<lgrid, dim3(tpb), 0, stream>>>(h1, h1q, bcnt, srcsS, boffs, W1T, b1, h2, h2q, N);
  fused_l3_head<<<lgrid, dim3(tpb), 0, stream>>>(h2, h2q, bcnt, srcsS, boffs, W2T, b2,
                                                 Wm1T, bm1, Wm2T, bm2, out, N, L);
}